// Round 1
// baseline (22438.374 us; speedup 1.0000x reference)
//
#include <hip/hip_runtime.h>
#include <hip/hip_fp16.h>

#define RB 64
#define RT 2048
#define RI 64
#define RH 512
#define C1F 0.9f
#define C2F 0.1f

// Pack W_hidden [RH][RH] f32 (row k, col j) -> f16-pair layout for per-thread
// coalesced dwordx4 streaming in the scan kernel.
// Entry e = (u*RH + j)*4 + q  (u in [0,64), j in [0,512), q in [0,4))
// holds half2( W[8u+2q][j], W[8u+2q+1][j] ).
// Thread j at iteration u loads 16B at uint4 index (u*RH + j): lanes are
// consecutive -> perfectly coalesced, and each step streams Wq fully
// sequentially (512 KB, L2-resident).
__global__ void prep_w_f16(const float* __restrict__ W, __half2* __restrict__ Wq) {
    int e = blockIdx.x * 256 + threadIdx.x;
    if (e >= (RH / 8) * RH * 4) return;
    int q = e & 3;
    int j = (e >> 2) & (RH - 1);
    int u = e >> 11;
    int k = 8 * u + 2 * q;
    Wq[e] = __floats2half2_rn(W[k * RH + j], W[(k + 1) * RH + j]);
}

// One workgroup per batch element (64 persistent workgroups).
// Thread j owns column j of h. tanh(h) is exchanged through LDS (f32,
// double-buffered -> exactly one __syncthreads per timestep).
__global__ __launch_bounds__(RH) void rnn_scan_f16(
        const float* __restrict__ x,      // [RB][RT][RI] f32
        const float* __restrict__ Win,    // [RI][RH]     f32
        const __half2* __restrict__ Wq,   // packed f16 W_hidden (see prep)
        const float* __restrict__ sigma,  // [RB][RT][RH] f32
        const float* __restrict__ h0,     // [RB][RH]     f32
        float* __restrict__ out)          // [RB][RT][RH] f32, then h_f [RB][RH]
{
    const int b = blockIdx.x;
    const int j = threadIdx.x;

    __shared__ __align__(16) float th[2][RH];   // tanh(h) double buffer, 4 KB

    // W_in column j kept in registers (64 VGPRs/thread, f32 exact).
    float win[RI];
    #pragma unroll
    for (int i = 0; i < RI; ++i) win[i] = Win[i * RH + j];

    float h = h0[b * RH + j];
    {
        float e2 = __expf(2.0f * h);
        th[0][j] = 1.0f - 2.0f / (e2 + 1.0f);
    }
    __syncthreads();

    const float* xrow = x + (size_t)b * RT * RI;
    const float* srow = sigma + (size_t)b * RT * RH;
    float*       orow = out + (size_t)b * RT * RH;
    const uint4* W4   = reinterpret_cast<const uint4*>(Wq);

    for (int t = 0; t < RT; ++t) {
        const int rb = t & 1;         // read buffer
        const int wb = rb ^ 1;        // write buffer

        // ---- input projection, f32 exact: wi = sum_i x[b,t,i] * W_in[i,j]
        // x row is wave-uniform -> scalar loads / L1 broadcast.
        float wi = 0.0f;
        const float4* xt4 = reinterpret_cast<const float4*>(xrow + (size_t)t * RI);
        #pragma unroll
        for (int i4 = 0; i4 < RI / 4; ++i4) {
            float4 xv = xt4[i4];
            wi = fmaf(xv.x, win[4 * i4 + 0], wi);
            wi = fmaf(xv.y, win[4 * i4 + 1], wi);
            wi = fmaf(xv.z, win[4 * i4 + 2], wi);
            wi = fmaf(xv.w, win[4 * i4 + 3], wi);
        }

        // ---- recurrent matvec: acc = sum_k tanh(h)[k] * W[k][j]
        // W streamed from L2 as f16 pairs; fmaf(__half2float(..)) is the
        // v_fma_mix_f32 pattern (f16 operand consumed directly, f32 accum).
        float a0 = 0.0f, a1 = 0.0f, a2 = 0.0f, a3 = 0.0f;
        #pragma unroll 8
        for (int u = 0; u < RH / 8; ++u) {
            uint4 wv = W4[u * RH + j];
            float4 ta = *reinterpret_cast<const float4*>(&th[rb][8 * u]);
            float4 tb = *reinterpret_cast<const float4*>(&th[rb][8 * u + 4]);
            __half2 w01 = __builtin_bit_cast(__half2, wv.x);
            __half2 w23 = __builtin_bit_cast(__half2, wv.y);
            __half2 w45 = __builtin_bit_cast(__half2, wv.z);
            __half2 w67 = __builtin_bit_cast(__half2, wv.w);
            a0 = fmaf(__half2float(w01.x), ta.x, a0);
            a1 = fmaf(__half2float(w01.y), ta.y, a1);
            a2 = fmaf(__half2float(w23.x), ta.z, a2);
            a3 = fmaf(__half2float(w23.y), ta.w, a3);
            a0 = fmaf(__half2float(w45.x), tb.x, a0);
            a1 = fmaf(__half2float(w45.y), tb.y, a1);
            a2 = fmaf(__half2float(w67.x), tb.z, a2);
            a3 = fmaf(__half2float(w67.y), tb.w, a3);
        }
        float acc = (a0 + a1) + (a2 + a3);

        // ---- state update (all f32)
        float hn = C1F * h + C2F * (wi + acc) + srow[(size_t)t * RH + j];
        orow[(size_t)t * RH + j] = hn;
        h = hn;

        // tanh(h) -> write buffer; one barrier publishes it for next step.
        float e2 = __expf(2.0f * h);
        th[wb][j] = 1.0f - 2.0f / (e2 + 1.0f);
        __syncthreads();
    }

    // final hidden state h_f
    out[(size_t)RB * RT * RH + (size_t)b * RH + j] = h;
}

extern "C" void kernel_launch(void* const* d_in, const int* in_sizes, int n_in,
                              void* d_out, int out_size, void* d_ws, size_t ws_size,
                              hipStream_t stream) {
    const float* x   = (const float*)d_in[0];
    const float* Win = (const float*)d_in[1];
    const float* Wh  = (const float*)d_in[2];
    const float* sg  = (const float*)d_in[3];
    const float* h0  = (const float*)d_in[4];
    float* out = (float*)d_out;

    __half2* Wq = (__half2*)d_ws;   // 512 KB of scratch for packed W_hidden

    hipLaunchKernelGGL(prep_w_f16, dim3(512), dim3(256), 0, stream, Wh, Wq);
    hipLaunchKernelGGL(rnn_scan_f16, dim3(RB), dim3(RH), 0, stream,
                       x, Win, Wq, sg, h0, out);
}

// Round 2
// 4913.796 us; speedup vs baseline: 4.5664x; 4.5664x over previous
//
#include <hip/hip_runtime.h>
#include <hip/hip_fp16.h>

typedef _Float16 h2f __attribute__((ext_vector_type(2)));

#define RB 64
#define RT 2048
#define RI 64
#define RH 512
#define C1F 0.9f
#define C2F 0.1f

// K-rows of the extended matvec: 64 u-groups (8 rows each) of W_hidden
// + 8 u-groups of W_in (the input projection folded into the recurrence).
#define NU     72
#define NU_REG 36                      // u 0..35   -> VGPR-resident (144 VGPRs)
#define NU_LDS 16                      // u 36..51  -> LDS-resident (128 KB)
#define NU_STR (NU - NU_REG - NU_LDS)  // u 52..71  -> streamed from L2 (160 KB/step)
#define THL    (RH + RI)               // extended state vector: [tanh(h); x_t]

static __device__ __forceinline__ h2f bch2(unsigned int v) {
    return __builtin_bit_cast(h2f, v);
}

#if __has_builtin(__builtin_amdgcn_fdot2)
#define DOT2(a, b, c) __builtin_amdgcn_fdot2((a), (b), (c), false)
#else
#define DOT2(a, b, c) fmaf((float)(a).x, (float)(b).x, fmaf((float)(a).y, (float)(b).y, (c)))
#endif

// Pack [W_hidden; W_in] into f16-pair stream P.
// half2 entry e = (u*RH + j)*4 + q holds rows (8u+2q, 8u+2q+1) of column j.
// uint4 entry (u*RH + j) therefore holds rows 8u..8u+7 of column j:
// coalesced 16B/lane loads in the scan kernel.
__global__ void prep_pack(const float* __restrict__ W, const float* __restrict__ Win,
                          h2f* __restrict__ P) {
    int e = blockIdx.x * 256 + threadIdx.x;
    if (e >= NU * RH * 4) return;
    int q = e & 3;
    int j = (e >> 2) & (RH - 1);
    int u = e >> 11;
    float v0, v1;
    if (u < 64) {                       // W_hidden rows
        int k = 8 * u + 2 * q;
        v0 = W[k * RH + j];
        v1 = W[(k + 1) * RH + j];
    } else {                            // W_in rows (unscaled; c2 applied to acc)
        int i = 8 * (u - 64) + 2 * q;
        v0 = Win[i * RH + j];
        v1 = Win[(i + 1) * RH + j];
    }
    h2f r;
    r.x = (_Float16)v0;
    r.y = (_Float16)v1;
    P[e] = r;
}

// One block per batch element; thread j owns output column j.
// W column lives in: 144 VGPRs (rows 0..287) + LDS (rows 288..415) + L2 stream
// (rows 416..511 and the 64 W_in rows). State vector [tanh(h); x_t] is f16 in
// LDS, double-buffered -> one barrier per step.
__global__ __launch_bounds__(RH, 2) void rnn_scan(
        const float* __restrict__ x,      // [RB][RT][RI] f32
        const float* __restrict__ sigma,  // [RB][RT][RH] f32
        const float* __restrict__ h0,     // [RB][RH]     f32
        const uint4* __restrict__ P,      // packed f16 [NU*RH] uint4
        float* __restrict__ out)          // [RB][RT][RH] f32, then h_f [RB][RH]
{
    const int b = blockIdx.x;
    const int j = threadIdx.x;

    __shared__ __align__(16) uint4    Wl[NU_LDS * RH];   // 128 KB
    __shared__ __align__(16) _Float16 th[2][THL];        // 2 x 1152 B

    // LDS-resident W segment (cooperative, coalesced)
    for (int e = j; e < NU_LDS * RH; e += RH)
        Wl[e] = P[(size_t)NU_REG * RH + e];

    // VGPR-resident W segment (static indices; launch_bounds allows 256 VGPRs)
    uint4 wr[NU_REG];
    #pragma unroll
    for (int u = 0; u < NU_REG; ++u)
        wr[u] = P[u * RH + j];

    const float* xrow = x + (size_t)b * RT * RI;
    const float* srow = sigma + (size_t)b * RT * RH;
    float*       orow = out + (size_t)b * RT * RH;

    float h = h0[b * RH + j];
    {
        float e2 = __expf(2.0f * h);
        th[0][j] = (_Float16)(1.0f - 2.0f / (e2 + 1.0f));
    }
    if (j < RI) th[0][RH + j] = (_Float16)xrow[j];
    __syncthreads();

    for (int t = 0; t < RT; ++t) {
        const uint4* thq = (const uint4*)th[t & 1];
        _Float16*    thw = th[(t & 1) ^ 1];

        // prefetch this step's sigma and next step's x early
        float sg = srow[(size_t)t * RH + j];
        float xn = 0.0f;
        if (j < RI && t + 1 < RT) xn = xrow[(size_t)(t + 1) * RI + j];

        // opaque zero: stops LICM from hoisting the 20 loop-invariant
        // streamed loads out of the t-loop (would spill wr[]).
        int ofs = 0;
        asm volatile("" : "+v"(ofs));
        const uint4* Pst = P + (size_t)(NU_REG + NU_LDS) * RH + j + ofs;

        // 4 independent accumulator chains (dep-latency ~4cyc > issue 2cyc)
        float a0 = 0.f, a1 = 0.f, a2 = 0.f, a3 = 0.f;

        #pragma unroll
        for (int u = 0; u < NU_REG; ++u) {
            uint4 tv = thq[u];            // uniform address -> LDS broadcast
            uint4 wv = wr[u];
            a0 = DOT2(bch2(wv.x), bch2(tv.x), a0);
            a1 = DOT2(bch2(wv.y), bch2(tv.y), a1);
            a2 = DOT2(bch2(wv.z), bch2(tv.z), a2);
            a3 = DOT2(bch2(wv.w), bch2(tv.w), a3);
        }
        #pragma unroll
        for (int u = 0; u < NU_LDS; ++u) {
            uint4 tv = thq[NU_REG + u];
            uint4 wv = Wl[u * RH + j];    // consecutive lanes -> conflict-free
            a0 = DOT2(bch2(wv.x), bch2(tv.x), a0);
            a1 = DOT2(bch2(wv.y), bch2(tv.y), a1);
            a2 = DOT2(bch2(wv.z), bch2(tv.z), a2);
            a3 = DOT2(bch2(wv.w), bch2(tv.w), a3);
        }
        #pragma unroll
        for (int u = 0; u < NU_STR; ++u) {
            uint4 tv = thq[NU_REG + NU_LDS + u];
            uint4 wv = Pst[u * RH];       // L2-hot 160 KB window, coalesced
            a0 = DOT2(bch2(wv.x), bch2(tv.x), a0);
            a1 = DOT2(bch2(wv.y), bch2(tv.y), a1);
            a2 = DOT2(bch2(wv.z), bch2(tv.z), a2);
            a3 = DOT2(bch2(wv.w), bch2(tv.w), a3);
        }

        float hn = C1F * h + C2F * ((a0 + a1) + (a2 + a3)) + sg;
        orow[(size_t)t * RH + j] = hn;
        h = hn;

        float e2 = __expf(2.0f * hn);
        thw[j] = (_Float16)(1.0f - 2.0f / (e2 + 1.0f));
        if (j < RI && t + 1 < RT) thw[RH + j] = (_Float16)xn;
        __syncthreads();
    }

    out[(size_t)RB * RT * RH + (size_t)b * RH + j] = h;
}

extern "C" void kernel_launch(void* const* d_in, const int* in_sizes, int n_in,
                              void* d_out, int out_size, void* d_ws, size_t ws_size,
                              hipStream_t stream) {
    const float* x   = (const float*)d_in[0];
    const float* Win = (const float*)d_in[1];
    const float* Wh  = (const float*)d_in[2];
    const float* sg  = (const float*)d_in[3];
    const float* h0  = (const float*)d_in[4];
    float* out = (float*)d_out;

    h2f* P = (h2f*)d_ws;   // 576 KB packed [W_hidden; W_in] in f16 pairs

    const int n_entries = NU * RH * 4;
    hipLaunchKernelGGL(prep_pack, dim3((n_entries + 255) / 256), dim3(256), 0, stream,
                       Wh, Win, P);
    hipLaunchKernelGGL(rnn_scan, dim3(RB), dim3(RH), 0, stream,
                       x, sg, h0, (const uint4*)d_ws, out);
}